// Round 1
// baseline (159.476 us; speedup 1.0000x reference)
//
#include <hip/hip_runtime.h>
#include <math.h>

#define BLOCK 256
#define PTS_PER_BLOCK 64
#define P_SPLIT 8        // threads cooperating on one point (j-range split)
#define TILE 2048        // coord points staged in LDS per pass (32 KB)
#define KNN 3

#define BIG 3.402823466e+38f

__global__ __launch_bounds__(BLOCK) void knn_loss_kernel(
    const float* __restrict__ pred,
    const float* __restrict__ coord,
    const float* __restrict__ target,
    float* __restrict__ out,
    int seg, int blocks_per_seg, float inv_total)
{
    __shared__ float4 sc[TILE];                                  // x,y,z,sumsq
    __shared__ float  cand_d[PTS_PER_BLOCK * P_SPLIT * KNN];     // 6 KB
    __shared__ int    cand_i[PTS_PER_BLOCK * P_SPLIT * KNN];     // 6 KB
    __shared__ float  red[PTS_PER_BLOCK];

    const int tid  = threadIdx.x;
    const int blk  = blockIdx.x;
    const int segi = blk / blocks_per_seg;
    const int pb   = (blk % blocks_per_seg) * PTS_PER_BLOCK;     // base point (within segment)
    const long segbase = (long)segi * seg;

    const int sub  = tid & (P_SPLIT - 1);
    const int prow = tid >> 3;                                   // 0..31
    const int p0 = pb + prow;                                    // local point idx
    const int p1 = pb + 32 + prow;

    // own coords + sumsq (ref: sq = sum(cp*cp))
    const float x0 = coord[(segbase + p0)*3 + 0];
    const float y0 = coord[(segbase + p0)*3 + 1];
    const float z0 = coord[(segbase + p0)*3 + 2];
    const float x1 = coord[(segbase + p1)*3 + 0];
    const float y1 = coord[(segbase + p1)*3 + 1];
    const float z1 = coord[(segbase + p1)*3 + 2];
    const float sq0 = x0*x0 + y0*y0 + z0*z0;
    const float sq1 = x1*x1 + y1*y1 + z1*z1;

    // per-thread top-3 (ascending distance), for both points
    float a0 = BIG, a1 = BIG, a2 = BIG;  int ai0 = -1, ai1 = -1, ai2 = -1;
    float b0 = BIG, b1 = BIG, b2 = BIG;  int bi0 = -1, bi1 = -1, bi2 = -1;

    for (int t0 = 0; t0 < seg; t0 += TILE) {
        __syncthreads();   // protect sc from previous pass readers
        const int tlen = (seg - t0 < TILE) ? (seg - t0) : TILE;
        for (int g = tid; g < tlen; g += BLOCK) {
            const long gp = segbase + t0 + g;
            const float cx = coord[gp*3 + 0];
            const float cy = coord[gp*3 + 1];
            const float cz = coord[gp*3 + 2];
            sc[g] = make_float4(cx, cy, cz, cx*cx + cy*cy + cz*cz);
        }
        __syncthreads();

        for (int j = sub; j < tlen; j += P_SPLIT) {
            const float4 c = sc[j];
            const int gj = t0 + j;

            // ----- point 0 -----
            {
                const float dot = x0*c.x + y0*c.y + z0*c.z;
                float d2 = fmaf(-2.0f, dot, sq0 + c.w);
                d2 = fmaxf(d2, 0.0f);
                if (gj == p0) d2 = BIG;          // exclude self (ref sets diag=-1, drops it)
                if (d2 < a2) {
                    if (d2 < a1) {
                        a2 = a1; ai2 = ai1;
                        if (d2 < a0) { a1 = a0; ai1 = ai0; a0 = d2; ai0 = gj; }
                        else         { a1 = d2; ai1 = gj; }
                    } else { a2 = d2; ai2 = gj; }
                }
            }
            // ----- point 1 -----
            {
                const float dot = x1*c.x + y1*c.y + z1*c.z;
                float d2 = fmaf(-2.0f, dot, sq1 + c.w);
                d2 = fmaxf(d2, 0.0f);
                if (gj == p1) d2 = BIG;
                if (d2 < b2) {
                    if (d2 < b1) {
                        b2 = b1; bi2 = bi1;
                        if (d2 < b0) { b1 = b0; bi1 = bi0; b0 = d2; bi0 = gj; }
                        else         { b1 = d2; bi1 = gj; }
                    } else { b2 = d2; bi2 = gj; }
                }
            }
        }
    }

    // dump per-thread candidates: layout [pt][sub][k]
    {
        const int base0 = (prow        * P_SPLIT + sub) * KNN;
        const int base1 = ((32 + prow) * P_SPLIT + sub) * KNN;
        cand_d[base0 + 0] = a0; cand_d[base0 + 1] = a1; cand_d[base0 + 2] = a2;
        cand_i[base0 + 0] = ai0; cand_i[base0 + 1] = ai1; cand_i[base0 + 2] = ai2;
        cand_d[base1 + 0] = b0; cand_d[base1 + 1] = b1; cand_d[base1 + 2] = b2;
        cand_i[base1 + 0] = bi0; cand_i[base1 + 1] = bi1; cand_i[base1 + 2] = bi2;
    }
    __syncthreads();

    float loss = 0.0f;
    if (tid < PTS_PER_BLOCK) {
        // merge 8 partial top-3 lists -> global top-3 for point (pb + tid)
        float m0 = BIG, m1 = BIG, m2 = BIG;  int n0 = -1, n1 = -1, n2 = -1;
        const int cb = tid * P_SPLIT * KNN;
        #pragma unroll
        for (int c = 0; c < P_SPLIT * KNN; ++c) {
            const float d = cand_d[cb + c];
            const int   i = cand_i[cb + c];
            if (d < m2) {
                if (d < m1) {
                    m2 = m1; n2 = n1;
                    if (d < m0) { m1 = m0; n1 = n0; m0 = d; n0 = i; }
                    else        { m1 = d; n1 = i; }
                } else { m2 = d; n2 = i; }
            }
        }

        // epilogue: sim/tsim for the 3 neighbors
        const long gp = segbase + pb + tid;
        const float px = pred[gp*3 + 0], py = pred[gp*3 + 1], pz = pred[gp*3 + 2];
        const float inp = sqrtf(px*px + py*py + pz*pz + 1e-8f) + 1e-10f;
        const float qx = px / inp, qy = py / inp, qz = pz / inp;
        const float tx = target[gp*3 + 0], ty = target[gp*3 + 1], tz = target[gp*3 + 2];

        const int nbr[KNN] = { n0, n1, n2 };
        #pragma unroll
        for (int k = 0; k < KNN; ++k) {
            const long gn = segbase + nbr[k];
            const float nx = pred[gn*3 + 0], ny = pred[gn*3 + 1], nz = pred[gn*3 + 2];
            const float ninp = sqrtf(nx*nx + ny*ny + nz*nz + 1e-8f) + 1e-10f;
            float sim = fabsf((nx*qx + ny*qy + nz*qz) / ninp);
            sim = fminf(sim, 1.0f);

            const float ux = target[gn*3 + 0], uy = target[gn*3 + 1], uz = target[gn*3 + 2];
            float tsim = fabsf(ux*tx + uy*ty + uz*tz);
            tsim = fminf(tsim, 1.0f);

            const float diff = sim - tsim;
            loss += diff * diff;
        }
        red[tid] = loss;
    }
    __syncthreads();

    if (tid == 0) {
        float s = 0.0f;
        #pragma unroll
        for (int i = 0; i < PTS_PER_BLOCK; ++i) s += red[i];
        atomicAdd(out, s * inv_total);
    }
}

extern "C" void kernel_launch(void* const* d_in, const int* in_sizes, int n_in,
                              void* d_out, int out_size, void* d_ws, size_t ws_size,
                              hipStream_t stream) {
    const float* pred   = (const float*)d_in[0];
    const float* coord  = (const float*)d_in[1];
    const float* target = (const float*)d_in[2];
    float* out = (float*)d_out;

    const int N    = in_sizes[0] / 3;
    const int nseg = in_sizes[3];
    const int seg  = N / nseg;

    hipMemsetAsync(out, 0, sizeof(float), stream);

    const int blocks_per_seg = seg / PTS_PER_BLOCK;
    const int nblocks = nseg * blocks_per_seg;
    const float inv_total = 1.0f / ((float)nseg * (float)seg * (float)KNN);

    knn_loss_kernel<<<nblocks, BLOCK, 0, stream>>>(pred, coord, target, out,
                                                   seg, blocks_per_seg, inv_total);
}

// Round 2
// 131.839 us; speedup vs baseline: 1.2096x; 1.2096x over previous
//
#include <hip/hip_runtime.h>
#include <math.h>

#define G 8                  // grid cells per dim
#define NCELL (G*G*G)        // 512
#define INV_CS 0.8f          // G / 10.0
#define CS 1.25f             // 10.0 / G
#define KNN 3
#define BIGF 3.402823466e+38f

#define BUILD_BLOCK 512
#define SEARCH_BLOCK 64

__device__ __forceinline__ int cell_of(float x, float y, float z) {
    int cx = (int)(x * INV_CS); cx = cx < 0 ? 0 : (cx > G-1 ? G-1 : cx);
    int cy = (int)(y * INV_CS); cy = cy < 0 ? 0 : (cy > G-1 ? G-1 : cy);
    int cz = (int)(z * INV_CS); cz = cz < 0 ? 0 : (cz > G-1 ? G-1 : cz);
    return (cx << 6) | (cy << 3) | cz;
}

// ---------------- Kernel 1: per-segment counting sort into cell order -------
__global__ __launch_bounds__(BUILD_BLOCK) void build_grid(
    const float* __restrict__ coord,
    float4* __restrict__ sorted,        // [nseg*seg]
    int* __restrict__ cellstart,        // [nseg*513]
    int seg)
{
    __shared__ int hist[NCELL];
    __shared__ int scanb[NCELL];
    __shared__ int start[NCELL + 1];

    const int tid = threadIdx.x;
    const int s   = blockIdx.x;
    const long segbase = (long)s * seg;

    hist[tid] = 0;
    __syncthreads();

    // pass 1: histogram
    for (int p = tid; p < seg; p += BUILD_BLOCK) {
        const float x = coord[(segbase + p)*3 + 0];
        const float y = coord[(segbase + p)*3 + 1];
        const float z = coord[(segbase + p)*3 + 2];
        atomicAdd(&hist[cell_of(x, y, z)], 1);
    }
    __syncthreads();

    // inclusive Hillis-Steele scan of hist (512 entries, 512 threads)
    scanb[tid] = hist[tid];
    __syncthreads();
    for (int off = 1; off < NCELL; off <<= 1) {
        const int add = (tid >= off) ? scanb[tid - off] : 0;
        __syncthreads();
        scanb[tid] += add;
        __syncthreads();
    }
    // exclusive starts
    start[tid] = scanb[tid] - hist[tid];
    if (tid == BUILD_BLOCK - 1) start[NCELL] = scanb[tid];
    __syncthreads();

    // write cell starts to global; init cursors (reuse hist)
    cellstart[s * (NCELL + 1) + tid] = start[tid];
    if (tid == 0) cellstart[s * (NCELL + 1) + NCELL] = start[NCELL];
    hist[tid] = start[tid];
    __syncthreads();

    // pass 2: scatter
    for (int p = tid; p < seg; p += BUILD_BLOCK) {
        const float x = coord[(segbase + p)*3 + 0];
        const float y = coord[(segbase + p)*3 + 1];
        const float z = coord[(segbase + p)*3 + 2];
        const int c = cell_of(x, y, z);
        const int slot = atomicAdd(&hist[c], 1);
        sorted[segbase + slot] = make_float4(x, y, z, __int_as_float(p));
    }
}

// ---------------- Kernel 2: per-point exact 3-NN via grid + loss ------------
__global__ __launch_bounds__(SEARCH_BLOCK) void knn_loss(
    const float4* __restrict__ sorted,
    const int* __restrict__ cellstart,
    const float* __restrict__ pred,
    const float* __restrict__ target,
    float* __restrict__ out,
    int seg, float inv_total)
{
    __shared__ int csl[NCELL + 1];

    const int t = blockIdx.x * SEARCH_BLOCK + threadIdx.x;  // sorted-order point
    const int s = t / 4096;        // seg == 4096 (blocks never straddle: 4096%64==0)
    const int j = t & 4095;        // slot within segment
    const long segbase = (long)s * seg;

    for (int i = threadIdx.x; i < NCELL + 1; i += SEARCH_BLOCK)
        csl[i] = cellstart[s * (NCELL + 1) + i];
    __syncthreads();

    const float4 me = sorted[segbase + j];
    const int myorig = __float_as_int(me.w);
    const int cx = (me.x * INV_CS) > (float)(G-1) ? G-1 : (int)(me.x * INV_CS);
    const int cy = (me.y * INV_CS) > (float)(G-1) ? G-1 : (int)(me.y * INV_CS);
    const int cz = (me.z * INV_CS) > (float)(G-1) ? G-1 : (int)(me.z * INV_CS);

    const double BIGP = __hiloint2double(__float_as_int(BIGF), -1);
    double m0, m1, m2;
    int R = 1;
    for (;;) {
        m0 = BIGP; m1 = BIGP; m2 = BIGP;
        const int x0 = max(cx - R, 0), x1 = min(cx + R, G-1);
        const int y0 = max(cy - R, 0), y1 = min(cy + R, G-1);
        const int z0 = max(cz - R, 0), z1 = min(cz + R, G-1);
        for (int gx = x0; gx <= x1; ++gx) {
            for (int gy = y0; gy <= y1; ++gy) {
                const int base = (gx << 6) | (gy << 3);
                const int q0 = csl[base + z0];
                const int q1 = csl[base + z1 + 1];
                for (int q = q0; q < q1; ++q) {
                    if (q == j) continue;                 // self
                    const float4 c = sorted[segbase + q];
                    const float dx = me.x - c.x;
                    const float dy = me.y - c.y;
                    const float dz = me.z - c.z;
                    const float d2 = fmaf(dx, dx, fmaf(dy, dy, dz * dz));
                    const double pk = __hiloint2double(__float_as_int(d2),
                                                       __float_as_int(c.w));
                    const double lo0 = fmin(m0, pk);
                    const double hi0 = fmax(m0, pk);
                    m0 = lo0;
                    const double lo1 = fmin(m1, hi0);
                    const double hi1 = fmax(m1, hi0);
                    m1 = lo1;
                    m2 = fmin(m2, hi1);
                }
            }
        }
        const float d3 = __uint_as_float((unsigned)__double2hiint(m2));
        const float g = (float)R * CS;
        if (d3 <= g * g || R >= G) break;
        ++R;   // exactness guard failed (rare, boundary points) — widen box
    }

    // ---- epilogue: sim/tsim loss for the 3 neighbors ----
    const int nbr[KNN] = { __double2loint(m0), __double2loint(m1), __double2loint(m2) };

    const long gp = segbase + myorig;
    const float px = pred[gp*3+0], py = pred[gp*3+1], pz = pred[gp*3+2];
    const float inp = sqrtf(px*px + py*py + pz*pz + 1e-8f) + 1e-10f;
    const float qx = px / inp, qy = py / inp, qz = pz / inp;
    const float tx = target[gp*3+0], ty = target[gp*3+1], tz = target[gp*3+2];

    float loss = 0.0f;
    #pragma unroll
    for (int k = 0; k < KNN; ++k) {
        const long gn = segbase + nbr[k];
        const float nx = pred[gn*3+0], ny = pred[gn*3+1], nz = pred[gn*3+2];
        const float ninp = sqrtf(nx*nx + ny*ny + nz*nz + 1e-8f) + 1e-10f;
        float sim = fabsf((nx*qx + ny*qy + nz*qz) / ninp);
        sim = fminf(sim, 1.0f);
        const float ux = target[gn*3+0], uy = target[gn*3+1], uz = target[gn*3+2];
        float tsim = fabsf(ux*tx + uy*ty + uz*tz);
        tsim = fminf(tsim, 1.0f);
        const float diff = sim - tsim;
        loss += diff * diff;
    }

    // wave reduction + one atomic per wave
    #pragma unroll
    for (int off = 32; off > 0; off >>= 1)
        loss += __shfl_down(loss, off);
    if (threadIdx.x == 0)
        atomicAdd(out, loss * inv_total);
}

extern "C" void kernel_launch(void* const* d_in, const int* in_sizes, int n_in,
                              void* d_out, int out_size, void* d_ws, size_t ws_size,
                              hipStream_t stream) {
    const float* pred   = (const float*)d_in[0];
    const float* coord  = (const float*)d_in[1];
    const float* target = (const float*)d_in[2];
    float* out = (float*)d_out;

    const int N    = in_sizes[0] / 3;
    const int nseg = in_sizes[3];
    const int seg  = N / nseg;           // 4096

    float4* sorted  = (float4*)d_ws;
    int* cellstart  = (int*)((char*)d_ws + (size_t)N * sizeof(float4));

    hipMemsetAsync(out, 0, sizeof(float), stream);

    build_grid<<<nseg, BUILD_BLOCK, 0, stream>>>(coord, sorted, cellstart, seg);

    const float inv_total = 1.0f / ((float)nseg * (float)seg * (float)KNN);
    knn_loss<<<N / SEARCH_BLOCK, SEARCH_BLOCK, 0, stream>>>(
        sorted, cellstart, pred, target, out, seg, inv_total);
}

// Round 3
// 80.997 us; speedup vs baseline: 1.9689x; 1.6277x over previous
//
#include <hip/hip_runtime.h>
#include <math.h>

#define G 8                  // grid cells per dim
#define NCELL (G*G*G)        // 512
#define INV_CS 0.8f          // G / 10.0
#define CS 1.25f             // 10.0 / G
#define KNN 3
#define BIGF 3.402823466e+38f

#define BUILD_BLOCK 1024
#define SEARCH_BLOCK 512
#define SPLIT 8                          // lanes cooperating per point
#define PTS_PER_SBLOCK (SEARCH_BLOCK / SPLIT)   // 64

__device__ __forceinline__ int cell_of(float x, float y, float z) {
    int cx = (int)(x * INV_CS); cx = cx < 0 ? 0 : (cx > G-1 ? G-1 : cx);
    int cy = (int)(y * INV_CS); cy = cy < 0 ? 0 : (cy > G-1 ? G-1 : cy);
    int cz = (int)(z * INV_CS); cz = cz < 0 ? 0 : (cz > G-1 ? G-1 : cz);
    return (cx << 6) | (cy << 3) | cz;
}

__device__ __forceinline__ void pk_insert(double pk, double& m0, double& m1, double& m2) {
    const double lo0 = fmin(m0, pk);
    const double hi0 = fmax(m0, pk);
    m0 = lo0;
    const double lo1 = fmin(m1, hi0);
    const double hi1 = fmax(m1, hi0);
    m1 = lo1;
    m2 = fmin(m2, hi1);
}

// ---------------- Kernel 1: per-segment counting sort into cell order -------
__global__ __launch_bounds__(BUILD_BLOCK) void build_grid(
    const float* __restrict__ coord,
    float4* __restrict__ sorted,        // [nseg*seg]
    int* __restrict__ cellstart,        // [nseg*513]
    float* __restrict__ out,
    int seg)
{
    __shared__ int hist[NCELL];
    __shared__ int scanb[NCELL];
    __shared__ int start[NCELL + 1];

    const int tid = threadIdx.x;
    const int s   = blockIdx.x;
    const long segbase = (long)s * seg;

    if (s == 0 && tid == 0) out[0] = 0.0f;   // replaces hipMemsetAsync

    if (tid < NCELL) hist[tid] = 0;
    __syncthreads();

    // pass 1: histogram
    for (int p = tid; p < seg; p += BUILD_BLOCK) {
        const float x = coord[(segbase + p)*3 + 0];
        const float y = coord[(segbase + p)*3 + 1];
        const float z = coord[(segbase + p)*3 + 2];
        atomicAdd(&hist[cell_of(x, y, z)], 1);
    }
    __syncthreads();

    // inclusive Hillis-Steele scan of hist (512 entries; barriers wave-uniform)
    if (tid < NCELL) scanb[tid] = hist[tid];
    __syncthreads();
    for (int off = 1; off < NCELL; off <<= 1) {
        int add = 0;
        if (tid < NCELL && tid >= off) add = scanb[tid - off];
        __syncthreads();
        if (tid < NCELL) scanb[tid] += add;
        __syncthreads();
    }
    if (tid < NCELL) {
        start[tid] = scanb[tid] - hist[tid];
        if (tid == NCELL - 1) start[NCELL] = scanb[tid];
    }
    __syncthreads();

    if (tid < NCELL) {
        cellstart[s * (NCELL + 1) + tid] = start[tid];
        if (tid == 0) cellstart[s * (NCELL + 1) + NCELL] = start[NCELL];
        hist[tid] = start[tid];        // reuse as cursors
    }
    __syncthreads();

    // pass 2: scatter
    for (int p = tid; p < seg; p += BUILD_BLOCK) {
        const float x = coord[(segbase + p)*3 + 0];
        const float y = coord[(segbase + p)*3 + 1];
        const float z = coord[(segbase + p)*3 + 2];
        const int c = cell_of(x, y, z);
        const int slot = atomicAdd(&hist[c], 1);
        sorted[segbase + slot] = make_float4(x, y, z, __int_as_float(p));
    }
}

// ---------------- Kernel 2: 8 lanes/point exact 3-NN via grid + loss --------
__global__ __launch_bounds__(SEARCH_BLOCK) void knn_loss(
    const float4* __restrict__ sorted,
    const int* __restrict__ cellstart,
    const float* __restrict__ pred,
    const float* __restrict__ target,
    float* __restrict__ out,
    int seg, float inv_total)
{
    __shared__ int csl[NCELL + 1];
    __shared__ float wred[SEARCH_BLOCK / 64];

    const int tid = threadIdx.x;
    const int sub = tid & (SPLIT - 1);
    const int pt  = blockIdx.x * PTS_PER_SBLOCK + (tid >> 3);  // sorted-order point
    const int s   = pt >> 12;      // seg == 4096; blocks never straddle segments
    const int j   = pt & 4095;     // slot within segment
    const long segbase = (long)s * seg;

    for (int i = tid; i < NCELL + 1; i += SEARCH_BLOCK)
        csl[i] = cellstart[s * (NCELL + 1) + i];
    __syncthreads();

    const float4 me = sorted[segbase + j];
    const int myorig = __float_as_int(me.w);
    const int cx = (me.x * INV_CS) > (float)(G-1) ? G-1 : (int)(me.x * INV_CS);
    const int cy = (me.y * INV_CS) > (float)(G-1) ? G-1 : (int)(me.y * INV_CS);
    const int cz = (me.z * INV_CS) > (float)(G-1) ? G-1 : (int)(me.z * INV_CS);

    const double BIGP = __hiloint2double(__float_as_int(BIGF), -1);
    double m0, m1, m2;
    int R = 1;
    for (;;) {
        m0 = BIGP; m1 = BIGP; m2 = BIGP;
        const int x0 = max(cx - R, 0), x1 = min(cx + R, G-1);
        const int y0 = max(cy - R, 0), y1 = min(cy + R, G-1);
        const int z0 = max(cz - R, 0), z1 = min(cz + R, G-1);
        for (int gx = x0; gx <= x1; ++gx) {
            for (int gy = y0; gy <= y1; ++gy) {
                const int base = (gx << 6) | (gy << 3);
                const int q0 = csl[base + z0];
                const int q1 = csl[base + z1 + 1];
                for (int q = q0 + sub; q < q1; q += SPLIT) {
                    const float4 c = sorted[segbase + q];
                    const float dx = me.x - c.x;
                    const float dy = me.y - c.y;
                    const float dz = me.z - c.z;
                    float d2 = fmaf(dx, dx, fmaf(dy, dy, dz * dz));
                    if (q == j) d2 = BIGF;                // self
                    pk_insert(__hiloint2double(__float_as_int(d2),
                                               __float_as_int(c.w)),
                              m0, m1, m2);
                }
            }
        }
        // butterfly merge across the 8 lanes of this point (partners always
        // share the same R-loop iteration count -> exec-mask safe)
        #pragma unroll
        for (int mask = 1; mask < SPLIT; mask <<= 1) {
            const double o0 = __shfl_xor(m0, mask);
            const double o1 = __shfl_xor(m1, mask);
            const double o2 = __shfl_xor(m2, mask);
            pk_insert(o0, m0, m1, m2);
            pk_insert(o1, m0, m1, m2);
            pk_insert(o2, m0, m1, m2);
        }
        const float d3 = __uint_as_float((unsigned)__double2hiint(m2));
        const float g = (float)R * CS;
        if (d3 <= g * g || R >= G) break;
        ++R;   // exactness guard failed (rare, boundary points) — widen box
    }

    // ---- epilogue: sim/tsim loss for the 3 neighbors (lane sub==0 only) ----
    float loss = 0.0f;
    if (sub == 0) {
        const int nbr[KNN] = { __double2loint(m0), __double2loint(m1), __double2loint(m2) };

        const long gp = segbase + myorig;
        const float px = pred[gp*3+0], py = pred[gp*3+1], pz = pred[gp*3+2];
        const float inp = sqrtf(px*px + py*py + pz*pz + 1e-8f) + 1e-10f;
        const float qx = px / inp, qy = py / inp, qz = pz / inp;
        const float tx = target[gp*3+0], ty = target[gp*3+1], tz = target[gp*3+2];

        #pragma unroll
        for (int k = 0; k < KNN; ++k) {
            const long gn = segbase + nbr[k];
            const float nx = pred[gn*3+0], ny = pred[gn*3+1], nz = pred[gn*3+2];
            const float ninp = sqrtf(nx*nx + ny*ny + nz*nz + 1e-8f) + 1e-10f;
            float sim = fabsf((nx*qx + ny*qy + nz*qz) / ninp);
            sim = fminf(sim, 1.0f);
            const float ux = target[gn*3+0], uy = target[gn*3+1], uz = target[gn*3+2];
            float tsim = fabsf(ux*tx + uy*ty + uz*tz);
            tsim = fminf(tsim, 1.0f);
            const float diff = sim - tsim;
            loss += diff * diff;
        }
    }

    // wave reduce -> LDS -> one atomic per block
    #pragma unroll
    for (int off = 32; off > 0; off >>= 1)
        loss += __shfl_down(loss, off);
    if ((tid & 63) == 0) wred[tid >> 6] = loss;
    __syncthreads();
    if (tid == 0) {
        float ssum = 0.0f;
        #pragma unroll
        for (int w = 0; w < SEARCH_BLOCK / 64; ++w) ssum += wred[w];
        atomicAdd(out, ssum * inv_total);
    }
}

extern "C" void kernel_launch(void* const* d_in, const int* in_sizes, int n_in,
                              void* d_out, int out_size, void* d_ws, size_t ws_size,
                              hipStream_t stream) {
    const float* pred   = (const float*)d_in[0];
    const float* coord  = (const float*)d_in[1];
    const float* target = (const float*)d_in[2];
    float* out = (float*)d_out;

    const int N    = in_sizes[0] / 3;
    const int nseg = in_sizes[3];
    const int seg  = N / nseg;           // 4096

    float4* sorted  = (float4*)d_ws;
    int* cellstart  = (int*)((char*)d_ws + (size_t)N * sizeof(float4));

    build_grid<<<nseg, BUILD_BLOCK, 0, stream>>>(coord, sorted, cellstart, out, seg);

    const float inv_total = 1.0f / ((float)nseg * (float)seg * (float)KNN);
    knn_loss<<<N / PTS_PER_SBLOCK, SEARCH_BLOCK, 0, stream>>>(
        sorted, cellstart, pred, target, out, seg, inv_total);
}